// Round 8
// baseline (256.898 us; speedup 1.0000x reference)
//
#include <hip/hip_runtime.h>
#include <math.h>

#define B_ 2
#define T_ 2048
#define D_ 1024
#define H_ 16
#define DH_ 64
#define NROWS (B_ * T_)        // 4096
#define QKV_N (3 * H_ * DH_)   // 3072

typedef __attribute__((ext_vector_type(8))) short short8v;  // 8 bf16
typedef __attribute__((ext_vector_type(4))) float f32x4;

// attention LDS granule swizzle (round-5/6, measured-correct)
#define SWZ(row) ((((row) & 7) ^ (((row) >> 3) & 7)))
// GEMM LDS granule swizzle (round-6, measured-correct)
#define GSWZ(row) (((row) >> 1) & 3)

static __device__ __forceinline__ unsigned short f2bf(float x) {
    unsigned u = __float_as_uint(x);
    u = (u + 0x7FFFu + ((u >> 16) & 1u)) >> 16;   // RNE
    return (unsigned short)u;
}
static __device__ __forceinline__ int packbf(float lo, float hi) {
    return (int)((unsigned)f2bf(lo) | ((unsigned)f2bf(hi) << 16));
}

// ---------------------------------------------------------------------------
// fp32 -> bf16 straight conversion (8 elems/thread)
// ---------------------------------------------------------------------------
__global__ __launch_bounds__(256)
void f32_to_bf16_k(const float* __restrict__ in, unsigned short* __restrict__ out,
                   int n8)
{
    const int i = blockIdx.x * 256 + threadIdx.x;
    if (i >= n8) return;
    const float4* p = (const float4*)in;
    float4 a = p[2 * i], b = p[2 * i + 1];
    int4 w;
    w.x = packbf(a.x, a.y); w.y = packbf(a.z, a.w);
    w.z = packbf(b.x, b.y); w.w = packbf(b.z, b.w);
    ((int4*)out)[i] = w;
}

// ---------------------------------------------------------------------------
// fp32 [R][C] -> bf16 [C][R] transpose-convert. 64x64 tiles, padded LDS.
// ---------------------------------------------------------------------------
__global__ __launch_bounds__(256)
void transpose_bf16_k(const float* __restrict__ in, unsigned short* __restrict__ out,
                      int R, int C)
{
    __shared__ float tile[64][65];
    const int r0 = blockIdx.y * 64, c0 = blockIdx.x * 64;
    const int tr = threadIdx.x >> 4;
    const int tc = (threadIdx.x & 15) * 4;
#pragma unroll
    for (int rr = 0; rr < 64; rr += 16) {
        float4 v = *(const float4*)(in + (size_t)(r0 + tr + rr) * C + c0 + tc);
        tile[tr + rr][tc + 0] = v.x; tile[tr + rr][tc + 1] = v.y;
        tile[tr + rr][tc + 2] = v.z; tile[tr + rr][tc + 3] = v.w;
    }
    __syncthreads();
    const int ow = threadIdx.x >> 2;
    const int os = (threadIdx.x & 3) * 16;
    int4 w0, w1;
    float s[16];
#pragma unroll
    for (int e = 0; e < 16; ++e) s[e] = tile[os + e][ow];
    w0.x = packbf(s[0], s[1]);   w0.y = packbf(s[2], s[3]);
    w0.z = packbf(s[4], s[5]);   w0.w = packbf(s[6], s[7]);
    w1.x = packbf(s[8], s[9]);   w1.y = packbf(s[10], s[11]);
    w1.z = packbf(s[12], s[13]); w1.w = packbf(s[14], s[15]);
    unsigned short* orow = out + (size_t)(c0 + ow) * R + r0 + os;
    *(int4*)(orow) = w0;
    *(int4*)(orow + 8) = w1;
}

// ---------------------------------------------------------------------------
// QKV GEMM: qkv = x @ Wqkv, epilogue routes bf16 into Qb (prescaled 0.125,
// [b,h,t,dh]), Kb ([b,h,t,dh]), Vtb (transposed, [b,h,dh,t]).
// `which = col>>10` is block-uniform (128-col tiles never straddle 1024).
// ---------------------------------------------------------------------------
__global__ __launch_bounds__(256)
void gemm_qkv(const unsigned short* __restrict__ A,
              const unsigned short* __restrict__ Bt,
              unsigned short* __restrict__ Qb,
              unsigned short* __restrict__ Kb,
              unsigned short* __restrict__ Vtb,
              int M, int N, int K)
{
    __shared__ __align__(16) unsigned short As[2][128 * 32];
    __shared__ __align__(16) unsigned short Bs[2][128 * 32];

    const int tid = threadIdx.x;
    const int w = tid >> 6, l = tid & 63;
    const int lhi = l >> 4, llo = l & 15;
    const int wr = w >> 1, wc = w & 1;
    const int bm = blockIdx.y * 128, bn = blockIdx.x * 128;

    const int srow = w * 32 + (l >> 2);
    const int sg   = l & 3;

    const unsigned short* Ab = A + (size_t)bm * K;
    const unsigned short* Bb = Bt + (size_t)bn * K;

    f32x4 acc[4][4];
#pragma unroll
    for (int mi = 0; mi < 4; ++mi)
#pragma unroll
        for (int ni = 0; ni < 4; ++ni) acc[mi][ni] = (f32x4){0.f, 0.f, 0.f, 0.f};

    short8v a0r, a1r, b0r, b1r;
    const int nt = K >> 5;

#define LOADT(t) do {                                                        \
        const size_t ko = (size_t)(t) * 32 + sg * 8;                         \
        a0r = *(const short8v*)(Ab + (size_t)srow * K + ko);                 \
        a1r = *(const short8v*)(Ab + (size_t)(srow + 16) * K + ko);         \
        b0r = *(const short8v*)(Bb + (size_t)srow * K + ko);                 \
        b1r = *(const short8v*)(Bb + (size_t)(srow + 16) * K + ko);         \
    } while (0)
#define WRITET(buf) do {                                                     \
        *(short8v*)&As[buf][srow * 32 + (sg ^ GSWZ(srow)) * 8] = a0r;        \
        *(short8v*)&As[buf][(srow + 16) * 32 + (sg ^ GSWZ(srow + 16)) * 8] = a1r; \
        *(short8v*)&Bs[buf][srow * 32 + (sg ^ GSWZ(srow)) * 8] = b0r;        \
        *(short8v*)&Bs[buf][(srow + 16) * 32 + (sg ^ GSWZ(srow + 16)) * 8] = b1r; \
    } while (0)

    LOADT(0);
    WRITET(0);
    __syncthreads();

    int cur = 0;
    for (int t = 0; t < nt; ++t) {
        if (t + 1 < nt) LOADT(t + 1);
        short8v af[4], bfr[4];
#pragma unroll
        for (int mi = 0; mi < 4; ++mi) {
            const int m = wr * 64 + mi * 16 + llo;
            af[mi] = *(const short8v*)&As[cur][m * 32 + (lhi ^ GSWZ(m)) * 8];
        }
#pragma unroll
        for (int ni = 0; ni < 4; ++ni) {
            const int n = wc * 64 + ni * 16 + llo;
            bfr[ni] = *(const short8v*)&Bs[cur][n * 32 + (lhi ^ GSWZ(n)) * 8];
        }
#pragma unroll
        for (int mi = 0; mi < 4; ++mi)
#pragma unroll
            for (int ni = 0; ni < 4; ++ni)
                acc[mi][ni] = __builtin_amdgcn_mfma_f32_16x16x32_bf16(
                    af[mi], bfr[ni], acc[mi][ni], 0, 0, 0);
        if (t + 1 < nt) WRITET(cur ^ 1);
        __syncthreads();
        cur ^= 1;
    }
#undef LOADT
#undef WRITET

    // epilogue: D row=(l>>4)*4+i, col=l&15. Route per `which` (block-uniform).
#pragma unroll
    for (int mi = 0; mi < 4; ++mi)
#pragma unroll
        for (int ni = 0; ni < 4; ++ni) {
            const int col = bn + wc * 64 + ni * 16 + llo;
            const int rb  = bm + wr * 64 + mi * 16 + lhi * 4;   // rows rb..rb+3
            const int hh = (col >> 6) & 15;
            const int dh = col & 63;
            const int bb = rb >> 11;
            const int tt = rb & 2047;
            const int which = col >> 10;
            if (which == 2) {
                int2 pk;
                pk.x = packbf(acc[mi][ni][0], acc[mi][ni][1]);
                pk.y = packbf(acc[mi][ni][2], acc[mi][ni][3]);
                *(int2*)&Vtb[((size_t)(bb * H_ + hh) * DH_ + dh) * T_ + tt] = pk;
            } else {
                unsigned short* dst = (which == 0 ? Qb : Kb)
                    + ((size_t)(bb * H_ + hh) * T_ + tt) * DH_ + dh;
                const float sc = (which == 0) ? 0.125f : 1.f;
#pragma unroll
                for (int i = 0; i < 4; ++i)
                    dst[(size_t)i * DH_] = f2bf(acc[mi][ni][i] * sc);
            }
        }
}

// ---------------------------------------------------------------------------
// bf16 MFMA GEMM (round-6, measured-correct): C_f32 = A_bf16 @ Bt_bf16^T.
// Used for the output projection.
// ---------------------------------------------------------------------------
__global__ __launch_bounds__(256)
void gemm_bt_bf16(const unsigned short* __restrict__ A,
                  const unsigned short* __restrict__ Bt,
                  float* __restrict__ C, int M, int N, int K)
{
    __shared__ __align__(16) unsigned short As[2][128 * 32];
    __shared__ __align__(16) unsigned short Bs[2][128 * 32];

    const int tid = threadIdx.x;
    const int w = tid >> 6, l = tid & 63;
    const int lhi = l >> 4, llo = l & 15;
    const int wr = w >> 1, wc = w & 1;
    const int bm = blockIdx.y * 128, bn = blockIdx.x * 128;

    const int srow = w * 32 + (l >> 2);
    const int sg   = l & 3;

    const unsigned short* Ab = A + (size_t)bm * K;
    const unsigned short* Bb = Bt + (size_t)bn * K;

    f32x4 acc[4][4];
#pragma unroll
    for (int mi = 0; mi < 4; ++mi)
#pragma unroll
        for (int ni = 0; ni < 4; ++ni) acc[mi][ni] = (f32x4){0.f, 0.f, 0.f, 0.f};

    short8v a0r, a1r, b0r, b1r;
    const int nt = K >> 5;

#define LOADT(t) do {                                                        \
        const size_t ko = (size_t)(t) * 32 + sg * 8;                         \
        a0r = *(const short8v*)(Ab + (size_t)srow * K + ko);                 \
        a1r = *(const short8v*)(Ab + (size_t)(srow + 16) * K + ko);         \
        b0r = *(const short8v*)(Bb + (size_t)srow * K + ko);                 \
        b1r = *(const short8v*)(Bb + (size_t)(srow + 16) * K + ko);         \
    } while (0)
#define WRITET(buf) do {                                                     \
        *(short8v*)&As[buf][srow * 32 + (sg ^ GSWZ(srow)) * 8] = a0r;        \
        *(short8v*)&As[buf][(srow + 16) * 32 + (sg ^ GSWZ(srow + 16)) * 8] = a1r; \
        *(short8v*)&Bs[buf][srow * 32 + (sg ^ GSWZ(srow)) * 8] = b0r;        \
        *(short8v*)&Bs[buf][(srow + 16) * 32 + (sg ^ GSWZ(srow + 16)) * 8] = b1r; \
    } while (0)

    LOADT(0);
    WRITET(0);
    __syncthreads();

    int cur = 0;
    for (int t = 0; t < nt; ++t) {
        if (t + 1 < nt) LOADT(t + 1);
        short8v af[4], bfr[4];
#pragma unroll
        for (int mi = 0; mi < 4; ++mi) {
            const int m = wr * 64 + mi * 16 + llo;
            af[mi] = *(const short8v*)&As[cur][m * 32 + (lhi ^ GSWZ(m)) * 8];
        }
#pragma unroll
        for (int ni = 0; ni < 4; ++ni) {
            const int n = wc * 64 + ni * 16 + llo;
            bfr[ni] = *(const short8v*)&Bs[cur][n * 32 + (lhi ^ GSWZ(n)) * 8];
        }
#pragma unroll
        for (int mi = 0; mi < 4; ++mi)
#pragma unroll
            for (int ni = 0; ni < 4; ++ni)
                acc[mi][ni] = __builtin_amdgcn_mfma_f32_16x16x32_bf16(
                    af[mi], bfr[ni], acc[mi][ni], 0, 0, 0);
        if (t + 1 < nt) WRITET(cur ^ 1);
        __syncthreads();
        cur ^= 1;
    }
#undef LOADT
#undef WRITET

#pragma unroll
    for (int mi = 0; mi < 4; ++mi)
#pragma unroll
        for (int ni = 0; ni < 4; ++ni) {
            const int col = bn + wc * 64 + ni * 16 + llo;
            const int rb = bm + wr * 64 + mi * 16 + lhi * 4;
#pragma unroll
            for (int i = 0; i < 4; ++i)
                C[(size_t)(rb + i) * N + col] = acc[mi][ni][i];
        }
}

// ---------------------------------------------------------------------------
// bf16-MFMA flash attention. Inputs pre-split bf16: Qb (prescaled),
// Kb [b,h,t,dh], Vtb [b,h,dh,t]. Staging = pure int4 copies, reg-prefetched.
// Grid: (32, H, B) = 1024 blocks, LONGEST-FIRST (qt = 31-bx) for LPT balance.
// ---------------------------------------------------------------------------
__global__ __launch_bounds__(256, 4)
void attn_mfma(const unsigned short* __restrict__ Qb,
               const unsigned short* __restrict__ Kb,
               const unsigned short* __restrict__ Vtb,
               const float* __restrict__ mask,
               unsigned short* __restrict__ out)
{
    __shared__ __align__(16) unsigned short Ks[64 * 64];   // [key][dh] swz
    __shared__ __align__(16) unsigned short Vs[64 * 64];   // [dh][key] swz
    __shared__ __align__(16) unsigned short Pl[4][16 * 64];
    __shared__ float ms[64];

    const int tid = threadIdx.x;
    const int w = tid >> 6, l = tid & 63;
    const int lhi = l >> 4, llo = l & 15;
    const int qt = 31 - (int)blockIdx.x;      // longest-first
    const int b = blockIdx.z, h = blockIdx.y;
    const int qb = qt * 64;

    const size_t bh = (size_t)(b * H_ + h);
    const unsigned short* Kbase = Kb + bh * T_ * DH_;
    const unsigned short* Vbase = Vtb + bh * DH_ * T_;

    const int sr  = tid >> 2;         // staging row (key for K, dh for V)
    const int sg0 = (tid & 3) * 2;    // granule pair

    // Q frags: direct bf16 load (prescale already applied)
    short8v qf[2];
    {
        const unsigned short* qrow = Qb + (bh * T_ + qb + w * 16 + llo) * DH_;
        qf[0] = *(const short8v*)(qrow + lhi * 8);
        qf[1] = *(const short8v*)(qrow + 32 + lhi * 8);
    }

    f32x4 acc[4];
#pragma unroll
    for (int ct = 0; ct < 4; ++ct) acc[ct] = (f32x4){0.f, 0.f, 0.f, 0.f};
    float mrow[4] = {-INFINITY, -INFINITY, -INFINITY, -INFINITY};
    float lrow[4] = {0.f, 0.f, 0.f, 0.f};

    int4 kr0, kr1, vr0, vr1;
    float mval;
#define LOADKV(t) do {                                                       \
        const int kk = (t) * 64;                                             \
        const unsigned short* kp = Kbase + (size_t)(kk + sr) * DH_ + sg0 * 8;\
        kr0 = *(const int4*)(kp);                                            \
        kr1 = *(const int4*)(kp + 8);                                        \
        const unsigned short* vp = Vbase + (size_t)sr * T_ + kk + sg0 * 8;   \
        vr0 = *(const int4*)(vp);                                            \
        vr1 = *(const int4*)(vp + 8);                                        \
        mval = (tid < 64) ? mask[b * T_ + kk + tid] : 0.f;                   \
    } while (0)

    LOADKV(0);

    for (int t0 = 0; t0 <= qt; ++t0) {
        const int k0 = t0 * 64;
        // publish current tile
        *(int4*)&Ks[(sr * 8 + (sg0 ^ SWZ(sr))) * 8] = kr0;
        *(int4*)&Ks[(sr * 8 + ((sg0 + 1) ^ SWZ(sr))) * 8] = kr1;
        *(int4*)&Vs[(sr * 8 + (sg0 ^ SWZ(sr))) * 8] = vr0;
        *(int4*)&Vs[(sr * 8 + ((sg0 + 1) ^ SWZ(sr))) * 8] = vr1;
        if (tid < 64) ms[tid] = mval;
        __syncthreads();

        // prefetch next tile (clamped)
        {
            const int tn = (t0 < qt) ? t0 + 1 : 0;
            LOADKV(tn);
        }

        // ---- S = Q @ K^T ----
        float p[4][4];
#pragma unroll
        for (int ct = 0; ct < 4; ++ct) {
            f32x4 a = (f32x4){0.f, 0.f, 0.f, 0.f};
#pragma unroll
            for (int kc = 0; kc < 2; ++kc) {
                const int row = ct * 16 + llo;
                const int G = kc * 4 + lhi;
                short8v kf = *(const short8v*)&Ks[(row * 8 + (G ^ SWZ(row))) * 8];
                a = __builtin_amdgcn_mfma_f32_16x16x32_bf16(qf[kc], kf, a, 0, 0, 0);
            }
            const int kg = k0 + ct * 16 + llo;
            const float amv = ms[ct * 16 + llo];
#pragma unroll
            for (int i = 0; i < 4; ++i) {
                const int qg = qb + w * 16 + lhi * 4 + i;
                const float s = a[i] * amv;
                p[ct][i] = (kg <= qg && amv != 0.f) ? s : -INFINITY;
            }
        }

        // ---- online softmax ----
        float corr[4], meff[4];
#pragma unroll
        for (int i = 0; i < 4; ++i) {
            float mx = fmaxf(fmaxf(p[0][i], p[1][i]), fmaxf(p[2][i], p[3][i]));
            mx = fmaxf(mx, __shfl_xor(mx, 1));
            mx = fmaxf(mx, __shfl_xor(mx, 2));
            mx = fmaxf(mx, __shfl_xor(mx, 4));
            mx = fmaxf(mx, __shfl_xor(mx, 8));
            const float mn = fmaxf(mrow[i], mx);
            meff[i] = (mn > -INFINITY) ? mn : 0.f;
            corr[i] = __expf(mrow[i] - meff[i]);
            mrow[i] = mn;
        }
#pragma unroll
        for (int i = 0; i < 4; ++i) {
#pragma unroll
            for (int ct = 0; ct < 4; ++ct)
                p[ct][i] = __expf(p[ct][i] - meff[i]);
            float sm = (p[0][i] + p[1][i]) + (p[2][i] + p[3][i]);
            sm += __shfl_xor(sm, 1);
            sm += __shfl_xor(sm, 2);
            sm += __shfl_xor(sm, 4);
            sm += __shfl_xor(sm, 8);
            lrow[i] = corr[i] * lrow[i] + sm;
#pragma unroll
            for (int ct2 = 0; ct2 < 4; ++ct2)
                acc[ct2][i] *= corr[i];
        }

        // ---- P -> wave-private LDS, read back as A-frags ----
        unsigned short* pw = Pl[w];
#pragma unroll
        for (int ct = 0; ct < 4; ++ct) {
            const int c = ct * 16 + llo;
#pragma unroll
            for (int i = 0; i < 4; ++i) {
                const int r = lhi * 4 + i;
                pw[(r * 8 + ((c >> 3) ^ SWZ(r))) * 8 + (c & 7)] = f2bf(p[ct][i]);
            }
        }
        asm volatile("s_waitcnt lgkmcnt(0)" ::: "memory");
        __builtin_amdgcn_sched_barrier(0);   // rule #18
        short8v pf[2];
#pragma unroll
        for (int kc = 0; kc < 2; ++kc) {
            const int G = kc * 4 + lhi;
            pf[kc] = *(const short8v*)&pw[(llo * 8 + (G ^ SWZ(llo))) * 8];
        }

        // ---- O += P @ V ----
#pragma unroll
        for (int ct2 = 0; ct2 < 4; ++ct2) {
#pragma unroll
            for (int kc = 0; kc < 2; ++kc) {
                const int row = ct2 * 16 + llo;
                const int G = kc * 4 + lhi;
                short8v vf = *(const short8v*)&Vs[(row * 8 + (G ^ SWZ(row))) * 8];
                acc[ct2] = __builtin_amdgcn_mfma_f32_16x16x32_bf16(
                    pf[kc], vf, acc[ct2], 0, 0, 0);
            }
        }
        __syncthreads();
    }
#undef LOADKV

    // ---- normalize + store bf16 [b,t,h*dh] ----
#pragma unroll
    for (int i = 0; i < 4; ++i) {
        const float invl = (lrow[i] > 0.f) ? 1.f / lrow[i] : 0.f;
        const int qg = qb + w * 16 + lhi * 4 + i;
        unsigned short* orow = out + (size_t)(b * T_ + qg) * (H_ * DH_) + h * DH_;
#pragma unroll
        for (int ct2 = 0; ct2 < 4; ++ct2)
            orow[ct2 * 16 + llo] = f2bf(acc[ct2][i] * invl);
    }
}

// ---------------------------------------------------------------------------
extern "C" void kernel_launch(void* const* d_in, const int* in_sizes, int n_in,
                              void* d_out, int out_size, void* d_ws, size_t ws_size,
                              hipStream_t stream)
{
    const float* x    = (const float*)d_in[0];
    const float* Wqkv = (const float*)d_in[1];
    const float* Wo   = (const float*)d_in[2];
    const float* mask = (const float*)d_in[3];
    float* out = (float*)d_out;

    // workspace layout (~48 MB)
    char* p = (char*)d_ws;
    unsigned short* xb     = (unsigned short*)p; p += (size_t)NROWS * D_ * 2;
    unsigned short* wqkv_t = (unsigned short*)p; p += (size_t)QKV_N * D_ * 2;
    unsigned short* wo_t   = (unsigned short*)p; p += (size_t)D_ * D_ * 2;
    unsigned short* Qb     = (unsigned short*)p; p += (size_t)NROWS * D_ * 2;
    unsigned short* Kb     = (unsigned short*)p; p += (size_t)NROWS * D_ * 2;
    unsigned short* Vtb    = (unsigned short*)p; p += (size_t)NROWS * D_ * 2;
    unsigned short* attnb  = (unsigned short*)p;

    // 0) conversions
    f32_to_bf16_k<<<(NROWS * D_ / 8 + 255) / 256, 256, 0, stream>>>(
        x, xb, NROWS * D_ / 8);
    transpose_bf16_k<<<dim3(QKV_N / 64, D_ / 64), 256, 0, stream>>>(
        Wqkv, wqkv_t, D_, QKV_N);
    transpose_bf16_k<<<dim3(D_ / 64, D_ / 64), 256, 0, stream>>>(
        Wo, wo_t, D_, D_);

    // 1) qkv GEMM -> Qb/Kb/Vtb (bf16, attention-ready layouts)
    gemm_qkv<<<dim3(QKV_N / 128, NROWS / 128), 256, 0, stream>>>(
        xb, wqkv_t, Qb, Kb, Vtb, NROWS, QKV_N, D_);

    // 2) attention -> attnb (bf16)
    attn_mfma<<<dim3(32, H_, B_), 256, 0, stream>>>(Qb, Kb, Vtb, mask, attnb);

    // 3) out = attn @ Wo
    gemm_bt_bf16<<<dim3(D_ / 128, NROWS / 128), 256, 0, stream>>>(
        attnb, wo_t, out, NROWS, D_, H_ * DH_);
}

// Round 9
// 228.628 us; speedup vs baseline: 1.1237x; 1.1237x over previous
//
#include <hip/hip_runtime.h>
#include <math.h>

#define B_ 2
#define T_ 2048
#define D_ 1024
#define H_ 16
#define DH_ 64
#define NROWS (B_ * T_)        // 4096
#define QKV_N (3 * H_ * DH_)   // 3072

typedef __attribute__((ext_vector_type(8))) short short8v;  // 8 bf16
typedef __attribute__((ext_vector_type(4))) float f32x4;

// attention LDS granule swizzle (round-5..8, measured-correct)
#define SWZ(row) ((((row) & 7) ^ (((row) >> 3) & 7)))
// GEMM LDS granule swizzle (round-6..8, measured-correct)
#define GSWZ(row) (((row) >> 1) & 3)

static __device__ __forceinline__ unsigned short f2bf(float x) {
    unsigned u = __float_as_uint(x);
    u = (u + 0x7FFFu + ((u >> 16) & 1u)) >> 16;   // RNE
    return (unsigned short)u;
}
static __device__ __forceinline__ int packbf(float lo, float hi) {
    return (int)((unsigned)f2bf(lo) | ((unsigned)f2bf(hi) << 16));
}

// ---------------------------------------------------------------------------
// fp32 -> bf16 straight conversion (8 elems/thread)
// ---------------------------------------------------------------------------
__global__ __launch_bounds__(256)
void f32_to_bf16_k(const float* __restrict__ in, unsigned short* __restrict__ out,
                   int n8)
{
    const int i = blockIdx.x * 256 + threadIdx.x;
    if (i >= n8) return;
    const float4* p = (const float4*)in;
    float4 a = p[2 * i], b = p[2 * i + 1];
    int4 w;
    w.x = packbf(a.x, a.y); w.y = packbf(a.z, a.w);
    w.z = packbf(b.x, b.y); w.w = packbf(b.z, b.w);
    ((int4*)out)[i] = w;
}

// ---------------------------------------------------------------------------
// fp32 [R][C] -> bf16 [C][R] transpose-convert. 64x64 tiles, padded LDS.
// ---------------------------------------------------------------------------
__global__ __launch_bounds__(256)
void transpose_bf16_k(const float* __restrict__ in, unsigned short* __restrict__ out,
                      int R, int C)
{
    __shared__ float tile[64][65];
    const int r0 = blockIdx.y * 64, c0 = blockIdx.x * 64;
    const int tr = threadIdx.x >> 4;
    const int tc = (threadIdx.x & 15) * 4;
#pragma unroll
    for (int rr = 0; rr < 64; rr += 16) {
        float4 v = *(const float4*)(in + (size_t)(r0 + tr + rr) * C + c0 + tc);
        tile[tr + rr][tc + 0] = v.x; tile[tr + rr][tc + 1] = v.y;
        tile[tr + rr][tc + 2] = v.z; tile[tr + rr][tc + 3] = v.w;
    }
    __syncthreads();
    const int ow = threadIdx.x >> 2;
    const int os = (threadIdx.x & 3) * 16;
    int4 w0, w1;
    float s[16];
#pragma unroll
    for (int e = 0; e < 16; ++e) s[e] = tile[os + e][ow];
    w0.x = packbf(s[0], s[1]);   w0.y = packbf(s[2], s[3]);
    w0.z = packbf(s[4], s[5]);   w0.w = packbf(s[6], s[7]);
    w1.x = packbf(s[8], s[9]);   w1.y = packbf(s[10], s[11]);
    w1.z = packbf(s[12], s[13]); w1.w = packbf(s[14], s[15]);
    unsigned short* orow = out + (size_t)(c0 + ow) * R + r0 + os;
    *(int4*)(orow) = w0;
    *(int4*)(orow + 8) = w1;
}

// ---------------------------------------------------------------------------
// QKV GEMM (round-7/8, measured-correct): epilogue routes bf16 into
// Qb (prescaled 0.125, [b,h,t,dh]), Kb ([b,h,t,dh]), Vtb ([b,h,dh,t]).
// ---------------------------------------------------------------------------
__global__ __launch_bounds__(256)
void gemm_qkv(const unsigned short* __restrict__ A,
              const unsigned short* __restrict__ Bt,
              unsigned short* __restrict__ Qb,
              unsigned short* __restrict__ Kb,
              unsigned short* __restrict__ Vtb,
              int M, int N, int K)
{
    __shared__ __align__(16) unsigned short As[2][128 * 32];
    __shared__ __align__(16) unsigned short Bs[2][128 * 32];

    const int tid = threadIdx.x;
    const int w = tid >> 6, l = tid & 63;
    const int lhi = l >> 4, llo = l & 15;
    const int wr = w >> 1, wc = w & 1;
    const int bm = blockIdx.y * 128, bn = blockIdx.x * 128;

    const int srow = w * 32 + (l >> 2);
    const int sg   = l & 3;

    const unsigned short* Ab = A + (size_t)bm * K;
    const unsigned short* Bb = Bt + (size_t)bn * K;

    f32x4 acc[4][4];
#pragma unroll
    for (int mi = 0; mi < 4; ++mi)
#pragma unroll
        for (int ni = 0; ni < 4; ++ni) acc[mi][ni] = (f32x4){0.f, 0.f, 0.f, 0.f};

    short8v a0r, a1r, b0r, b1r;
    const int nt = K >> 5;

#define LOADT(t) do {                                                        \
        const size_t ko = (size_t)(t) * 32 + sg * 8;                         \
        a0r = *(const short8v*)(Ab + (size_t)srow * K + ko);                 \
        a1r = *(const short8v*)(Ab + (size_t)(srow + 16) * K + ko);         \
        b0r = *(const short8v*)(Bb + (size_t)srow * K + ko);                 \
        b1r = *(const short8v*)(Bb + (size_t)(srow + 16) * K + ko);         \
    } while (0)
#define WRITET(buf) do {                                                     \
        *(short8v*)&As[buf][srow * 32 + (sg ^ GSWZ(srow)) * 8] = a0r;        \
        *(short8v*)&As[buf][(srow + 16) * 32 + (sg ^ GSWZ(srow + 16)) * 8] = a1r; \
        *(short8v*)&Bs[buf][srow * 32 + (sg ^ GSWZ(srow)) * 8] = b0r;        \
        *(short8v*)&Bs[buf][(srow + 16) * 32 + (sg ^ GSWZ(srow + 16)) * 8] = b1r; \
    } while (0)

    LOADT(0);
    WRITET(0);
    __syncthreads();

    int cur = 0;
    for (int t = 0; t < nt; ++t) {
        if (t + 1 < nt) LOADT(t + 1);
        short8v af[4], bfr[4];
#pragma unroll
        for (int mi = 0; mi < 4; ++mi) {
            const int m = wr * 64 + mi * 16 + llo;
            af[mi] = *(const short8v*)&As[cur][m * 32 + (lhi ^ GSWZ(m)) * 8];
        }
#pragma unroll
        for (int ni = 0; ni < 4; ++ni) {
            const int n = wc * 64 + ni * 16 + llo;
            bfr[ni] = *(const short8v*)&Bs[cur][n * 32 + (lhi ^ GSWZ(n)) * 8];
        }
#pragma unroll
        for (int mi = 0; mi < 4; ++mi)
#pragma unroll
            for (int ni = 0; ni < 4; ++ni)
                acc[mi][ni] = __builtin_amdgcn_mfma_f32_16x16x32_bf16(
                    af[mi], bfr[ni], acc[mi][ni], 0, 0, 0);
        if (t + 1 < nt) WRITET(cur ^ 1);
        __syncthreads();
        cur ^= 1;
    }
#undef LOADT
#undef WRITET

#pragma unroll
    for (int mi = 0; mi < 4; ++mi)
#pragma unroll
        for (int ni = 0; ni < 4; ++ni) {
            const int col = bn + wc * 64 + ni * 16 + llo;
            const int rb  = bm + wr * 64 + mi * 16 + lhi * 4;
            const int hh = (col >> 6) & 15;
            const int dh = col & 63;
            const int bb = rb >> 11;
            const int tt = rb & 2047;
            const int which = col >> 10;
            if (which == 2) {
                int2 pk;
                pk.x = packbf(acc[mi][ni][0], acc[mi][ni][1]);
                pk.y = packbf(acc[mi][ni][2], acc[mi][ni][3]);
                *(int2*)&Vtb[((size_t)(bb * H_ + hh) * DH_ + dh) * T_ + tt] = pk;
            } else {
                unsigned short* dst = (which == 0 ? Qb : Kb)
                    + ((size_t)(bb * H_ + hh) * T_ + tt) * DH_ + dh;
                const float sc = (which == 0) ? 0.125f : 1.f;
#pragma unroll
                for (int i = 0; i < 4; ++i)
                    dst[(size_t)i * DH_] = f2bf(acc[mi][ni][i] * sc);
            }
        }
}

// ---------------------------------------------------------------------------
// bf16 MFMA GEMM (round-6..8, measured-correct): C_f32 = A_bf16 @ Bt_bf16^T.
// ---------------------------------------------------------------------------
__global__ __launch_bounds__(256)
void gemm_bt_bf16(const unsigned short* __restrict__ A,
                  const unsigned short* __restrict__ Bt,
                  float* __restrict__ C, int M, int N, int K)
{
    __shared__ __align__(16) unsigned short As[2][128 * 32];
    __shared__ __align__(16) unsigned short Bs[2][128 * 32];

    const int tid = threadIdx.x;
    const int w = tid >> 6, l = tid & 63;
    const int lhi = l >> 4, llo = l & 15;
    const int wr = w >> 1, wc = w & 1;
    const int bm = blockIdx.y * 128, bn = blockIdx.x * 128;

    const int srow = w * 32 + (l >> 2);
    const int sg   = l & 3;

    const unsigned short* Ab = A + (size_t)bm * K;
    const unsigned short* Bb = Bt + (size_t)bn * K;

    f32x4 acc[4][4];
#pragma unroll
    for (int mi = 0; mi < 4; ++mi)
#pragma unroll
        for (int ni = 0; ni < 4; ++ni) acc[mi][ni] = (f32x4){0.f, 0.f, 0.f, 0.f};

    short8v a0r, a1r, b0r, b1r;
    const int nt = K >> 5;

#define LOADT(t) do {                                                        \
        const size_t ko = (size_t)(t) * 32 + sg * 8;                         \
        a0r = *(const short8v*)(Ab + (size_t)srow * K + ko);                 \
        a1r = *(const short8v*)(Ab + (size_t)(srow + 16) * K + ko);         \
        b0r = *(const short8v*)(Bb + (size_t)srow * K + ko);                 \
        b1r = *(const short8v*)(Bb + (size_t)(srow + 16) * K + ko);         \
    } while (0)
#define WRITET(buf) do {                                                     \
        *(short8v*)&As[buf][srow * 32 + (sg ^ GSWZ(srow)) * 8] = a0r;        \
        *(short8v*)&As[buf][(srow + 16) * 32 + (sg ^ GSWZ(srow + 16)) * 8] = a1r; \
        *(short8v*)&Bs[buf][srow * 32 + (sg ^ GSWZ(srow)) * 8] = b0r;        \
        *(short8v*)&Bs[buf][(srow + 16) * 32 + (sg ^ GSWZ(srow + 16)) * 8] = b1r; \
    } while (0)

    LOADT(0);
    WRITET(0);
    __syncthreads();

    int cur = 0;
    for (int t = 0; t < nt; ++t) {
        if (t + 1 < nt) LOADT(t + 1);
        short8v af[4], bfr[4];
#pragma unroll
        for (int mi = 0; mi < 4; ++mi) {
            const int m = wr * 64 + mi * 16 + llo;
            af[mi] = *(const short8v*)&As[cur][m * 32 + (lhi ^ GSWZ(m)) * 8];
        }
#pragma unroll
        for (int ni = 0; ni < 4; ++ni) {
            const int n = wc * 64 + ni * 16 + llo;
            bfr[ni] = *(const short8v*)&Bs[cur][n * 32 + (lhi ^ GSWZ(n)) * 8];
        }
#pragma unroll
        for (int mi = 0; mi < 4; ++mi)
#pragma unroll
            for (int ni = 0; ni < 4; ++ni)
                acc[mi][ni] = __builtin_amdgcn_mfma_f32_16x16x32_bf16(
                    af[mi], bfr[ni], acc[mi][ni], 0, 0, 0);
        if (t + 1 < nt) WRITET(cur ^ 1);
        __syncthreads();
        cur ^= 1;
    }
#undef LOADT
#undef WRITET

#pragma unroll
    for (int mi = 0; mi < 4; ++mi)
#pragma unroll
        for (int ni = 0; ni < 4; ++ni) {
            const int col = bn + wc * 64 + ni * 16 + llo;
            const int rb = bm + wr * 64 + mi * 16 + lhi * 4;
#pragma unroll
            for (int i = 0; i < 4; ++i)
                C[(size_t)(rb + i) * N + col] = acc[mi][ni][i];
        }
}

// ---------------------------------------------------------------------------
// bf16-MFMA flash attention, SWAPPED operands (m214 structure):
//   S[key][q] = mfma(K_frag, Q_frag)  -> lane owns query q=llo, 16 keys
//   in-lane;  softmax reduce = 15 VALU fmax + 2-deep shfl (was 8x 4-deep).
//   O^T[dh][q] = mfma(V_frag, P_frag) -> rescale/normalize in-lane.
// All LDS/operand read patterns byte-identical to round-8 (proven).
// Epilogue: O^T transposed through wave-private Pl -> coalesced b128 stores.
// ---------------------------------------------------------------------------
__global__ __launch_bounds__(256, 4)
void attn_mfma(const unsigned short* __restrict__ Qb,
               const unsigned short* __restrict__ Kb,
               const unsigned short* __restrict__ Vtb,
               const float* __restrict__ mask,
               unsigned short* __restrict__ out)
{
    __shared__ __align__(16) unsigned short Ks[64 * 64];   // [key][dh] swz
    __shared__ __align__(16) unsigned short Vs[64 * 64];   // [dh][key] swz
    __shared__ __align__(16) unsigned short Pl[4][16 * 64];
    __shared__ float ms[64];

    const int tid = threadIdx.x;
    const int w = tid >> 6, l = tid & 63;
    const int lhi = l >> 4, llo = l & 15;
    const int qt = 31 - (int)blockIdx.x;      // longest-first (LPT)
    const int b = blockIdx.z, h = blockIdx.y;
    const int qb = qt * 64;

    const size_t bh = (size_t)(b * H_ + h);
    const unsigned short* Kbase = Kb + bh * T_ * DH_;
    const unsigned short* Vbase = Vtb + bh * DH_ * T_;

    const int sr  = tid >> 2;
    const int sg0 = (tid & 3) * 2;

    const int qg = qb + w * 16 + llo;         // this lane's query

    // Q B-frags (col=llo=q, k=lhi*8+e): same loads as round-8
    short8v qf[2];
    {
        const unsigned short* qrow = Qb + (bh * T_ + qg) * DH_;
        qf[0] = *(const short8v*)(qrow + lhi * 8);
        qf[1] = *(const short8v*)(qrow + 32 + lhi * 8);
    }

    // acc = O^T: acc[ct2][i] = O[dh=16ct2+4lhi+i][q=llo]
    f32x4 acc[4];
#pragma unroll
    for (int ct = 0; ct < 4; ++ct) acc[ct] = (f32x4){0.f, 0.f, 0.f, 0.f};
    float mrun = -INFINITY, lrun = 0.f;

    int4 kr0, kr1, vr0, vr1;
    float mval;
#define LOADKV(t) do {                                                       \
        const int kk = (t) * 64;                                             \
        const unsigned short* kp = Kbase + (size_t)(kk + sr) * DH_ + sg0 * 8;\
        kr0 = *(const int4*)(kp);                                            \
        kr1 = *(const int4*)(kp + 8);                                        \
        const unsigned short* vp = Vbase + (size_t)sr * T_ + kk + sg0 * 8;   \
        vr0 = *(const int4*)(vp);                                            \
        vr1 = *(const int4*)(vp + 8);                                        \
        mval = (tid < 64) ? mask[b * T_ + kk + tid] : 0.f;                   \
    } while (0)

    LOADKV(0);

    for (int t0 = 0; t0 <= qt; ++t0) {
        const int k0 = t0 * 64;
        *(int4*)&Ks[(sr * 8 + (sg0 ^ SWZ(sr))) * 8] = kr0;
        *(int4*)&Ks[(sr * 8 + ((sg0 + 1) ^ SWZ(sr))) * 8] = kr1;
        *(int4*)&Vs[(sr * 8 + (sg0 ^ SWZ(sr))) * 8] = vr0;
        *(int4*)&Vs[(sr * 8 + ((sg0 + 1) ^ SWZ(sr))) * 8] = vr1;
        if (tid < 64) ms[tid] = mval;
        __syncthreads();

        {
            const int tn = (t0 < qt) ? t0 + 1 : 0;
            LOADKV(tn);
        }

        // wave-level skip: tile fully above this wave's queries
        if (k0 <= qb + w * 16 + 15) {
            // ---- S = K @ Q^T -> S[key][q]; lane: q=llo, keys 16ct+4lhi+i
            float p[4][4];
#pragma unroll
            for (int ct = 0; ct < 4; ++ct) {
                f32x4 a = (f32x4){0.f, 0.f, 0.f, 0.f};
#pragma unroll
                for (int kc = 0; kc < 2; ++kc) {
                    const int row = ct * 16 + llo;      // key row in Ks
                    const int G = kc * 4 + lhi;
                    short8v kf = *(const short8v*)&Ks[(row * 8 + (G ^ SWZ(row))) * 8];
                    a = __builtin_amdgcn_mfma_f32_16x16x32_bf16(kf, qf[kc], a, 0, 0, 0);
                }
#pragma unroll
                for (int i = 0; i < 4; ++i) {
                    const int kg = k0 + ct * 16 + 4 * lhi + i;
                    const float amv = ms[ct * 16 + 4 * lhi + i];
                    const float s = a[i] * amv;
                    p[ct][i] = (kg <= qg && amv != 0.f) ? s : -INFINITY;
                }
            }

            // ---- online softmax: in-lane 16-reduce + 2-deep shfl ----
            float mx;
            {
                float m0 = fmaxf(fmaxf(p[0][0], p[0][1]), fmaxf(p[0][2], p[0][3]));
                float m1 = fmaxf(fmaxf(p[1][0], p[1][1]), fmaxf(p[1][2], p[1][3]));
                float m2 = fmaxf(fmaxf(p[2][0], p[2][1]), fmaxf(p[2][2], p[2][3]));
                float m3 = fmaxf(fmaxf(p[3][0], p[3][1]), fmaxf(p[3][2], p[3][3]));
                mx = fmaxf(fmaxf(m0, m1), fmaxf(m2, m3));
            }
            mx = fmaxf(mx, __shfl_xor(mx, 16));
            mx = fmaxf(mx, __shfl_xor(mx, 32));
            const float mn = fmaxf(mrun, mx);
            const float me = (mn > -INFINITY) ? mn : 0.f;
            const float corr = __expf(mrun - me);
            mrun = mn;

#pragma unroll
            for (int ct = 0; ct < 4; ++ct)
#pragma unroll
                for (int i = 0; i < 4; ++i)
                    p[ct][i] = __expf(p[ct][i] - me);   // exp(-inf)=0

            float sm;
            {
                float s0 = (p[0][0] + p[0][1]) + (p[0][2] + p[0][3]);
                float s1 = (p[1][0] + p[1][1]) + (p[1][2] + p[1][3]);
                float s2 = (p[2][0] + p[2][1]) + (p[2][2] + p[2][3]);
                float s3 = (p[3][0] + p[3][1]) + (p[3][2] + p[3][3]);
                sm = (s0 + s1) + (s2 + s3);
            }
            sm += __shfl_xor(sm, 16);
            sm += __shfl_xor(sm, 32);
            lrun = corr * lrun + sm;
#pragma unroll
            for (int ct2 = 0; ct2 < 4; ++ct2)
#pragma unroll
                for (int i = 0; i < 4; ++i)
                    acc[ct2][i] *= corr;

            // ---- P -> Pl[q=llo][key], packed int2 writes ----
            unsigned short* pw = Pl[w];
#pragma unroll
            for (int ct = 0; ct < 4; ++ct) {
                int2 pk;
                pk.x = packbf(p[ct][0], p[ct][1]);
                pk.y = packbf(p[ct][2], p[ct][3]);
                const int k3 = 2 * ct + (lhi >> 1);   // key>>3
                *(int2*)&pw[(llo * 8 + (k3 ^ SWZ(llo))) * 8 + 4 * (lhi & 1)] = pk;
            }
            asm volatile("s_waitcnt lgkmcnt(0)" ::: "memory");
            __builtin_amdgcn_sched_barrier(0);   // rule #18
            short8v pf[2];
#pragma unroll
            for (int kc = 0; kc < 2; ++kc) {
                const int G = kc * 4 + lhi;
                pf[kc] = *(const short8v*)&pw[(llo * 8 + (G ^ SWZ(llo))) * 8];
            }

            // ---- O^T += V^T @ P : acc[ct2] covers dh block [16ct2,16ct2+16)
#pragma unroll
            for (int ct2 = 0; ct2 < 4; ++ct2) {
#pragma unroll
                for (int kc = 0; kc < 2; ++kc) {
                    const int row = ct2 * 16 + llo;     // Vs row = dh
                    const int G = kc * 4 + lhi;
                    short8v vf = *(const short8v*)&Vs[(row * 8 + (G ^ SWZ(row))) * 8];
                    acc[ct2] = __builtin_amdgcn_mfma_f32_16x16x32_bf16(
                        vf, pf[kc], acc[ct2], 0, 0, 0);
                }
            }
        }
        __syncthreads();
    }
#undef LOADKV

    // ---- epilogue: normalize, transpose O^T via wave-private Pl, store ----
    {
        const float invl = (lrun > 0.f) ? 1.f / lrun : 0.f;
        unsigned short* pw = Pl[w];
#pragma unroll
        for (int ct2 = 0; ct2 < 4; ++ct2) {
            int2 ok;
            ok.x = packbf(acc[ct2][0] * invl, acc[ct2][1] * invl);
            ok.y = packbf(acc[ct2][2] * invl, acc[ct2][3] * invl);
            const int d3 = 2 * ct2 + (lhi >> 1);   // dh>>3
            *(int2*)&pw[(llo * 8 + (d3 ^ SWZ(llo))) * 8 + 4 * (lhi & 1)] = ok;
        }
        asm volatile("s_waitcnt lgkmcnt(0)" ::: "memory");
        __builtin_amdgcn_sched_barrier(0);
        const int r  = l >> 2;           // q row within wave
        const int g2 = (l & 3) * 2;      // dh granule pair
        short8v o0 = *(const short8v*)&pw[(r * 8 + (g2 ^ SWZ(r))) * 8];
        short8v o1 = *(const short8v*)&pw[(r * 8 + ((g2 + 1) ^ SWZ(r))) * 8];
        unsigned short* orow = out + (size_t)(b * T_ + qb + w * 16 + r) * (H_ * DH_)
                               + h * DH_ + (l & 3) * 16;
        *(short8v*)(orow) = o0;
        *(short8v*)(orow + 8) = o1;
    }
}

// ---------------------------------------------------------------------------
extern "C" void kernel_launch(void* const* d_in, const int* in_sizes, int n_in,
                              void* d_out, int out_size, void* d_ws, size_t ws_size,
                              hipStream_t stream)
{
    const float* x    = (const float*)d_in[0];
    const float* Wqkv = (const float*)d_in[1];
    const float* Wo   = (const float*)d_in[2];
    const float* mask = (const float*)d_in[3];
    float* out = (float*)d_out;

    // workspace layout (~48 MB)
    char* p = (char*)d_ws;
    unsigned short* xb     = (unsigned short*)p; p += (size_t)NROWS * D_ * 2;
    unsigned short* wqkv_t = (unsigned short*)p; p += (size_t)QKV_N * D_ * 2;
    unsigned short* wo_t   = (unsigned short*)p; p += (size_t)D_ * D_ * 2;
    unsigned short* Qb     = (unsigned short*)p; p += (size_t)NROWS * D_ * 2;
    unsigned short* Kb     = (unsigned short*)p; p += (size_t)NROWS * D_ * 2;
    unsigned short* Vtb    = (unsigned short*)p; p += (size_t)NROWS * D_ * 2;
    unsigned short* attnb  = (unsigned short*)p;

    f32_to_bf16_k<<<(NROWS * D_ / 8 + 255) / 256, 256, 0, stream>>>(
        x, xb, NROWS * D_ / 8);
    transpose_bf16_k<<<dim3(QKV_N / 64, D_ / 64), 256, 0, stream>>>(
        Wqkv, wqkv_t, D_, QKV_N);
    transpose_bf16_k<<<dim3(D_ / 64, D_ / 64), 256, 0, stream>>>(
        Wo, wo_t, D_, D_);

    gemm_qkv<<<dim3(QKV_N / 128, NROWS / 128), 256, 0, stream>>>(
        xb, wqkv_t, Qb, Kb, Vtb, NROWS, QKV_N, D_);

    attn_mfma<<<dim3(32, H_, B_), 256, 0, stream>>>(Qb, Kb, Vtb, mask, attnb);

    gemm_bt_bf16<<<dim3(D_ / 128, NROWS / 128), 256, 0, stream>>>(
        attnb, wo_t, out, NROWS, D_, H_ * DH_);
}

// Round 10
// 205.178 us; speedup vs baseline: 1.2521x; 1.1143x over previous
//
#include <hip/hip_runtime.h>
#include <math.h>

#define B_ 2
#define T_ 2048
#define D_ 1024
#define H_ 16
#define DH_ 64
#define NROWS (B_ * T_)        // 4096
#define QKV_N (3 * H_ * DH_)   // 3072

typedef __attribute__((ext_vector_type(8))) short short8v;  // 8 bf16
typedef __attribute__((ext_vector_type(4))) float f32x4;

// attention LDS granule swizzle (round-5..9, measured-correct)
#define SWZ(row) ((((row) & 7) ^ (((row) >> 3) & 7)))
// GEMM LDS granule swizzle (round-6..9, measured-correct)
#define GSWZ(row) (((row) >> 1) & 3)

static __device__ __forceinline__ unsigned short f2bf(float x) {
    unsigned u = __float_as_uint(x);
    u = (u + 0x7FFFu + ((u >> 16) & 1u)) >> 16;   // RNE
    return (unsigned short)u;
}
static __device__ __forceinline__ int packbf(float lo, float hi) {
    return (int)((unsigned)f2bf(lo) | ((unsigned)f2bf(hi) << 16));
}

// ---------------------------------------------------------------------------
// fp32 -> bf16 straight conversion (8 elems/thread)
// ---------------------------------------------------------------------------
__global__ __launch_bounds__(256)
void f32_to_bf16_k(const float* __restrict__ in, unsigned short* __restrict__ out,
                   int n8)
{
    const int i = blockIdx.x * 256 + threadIdx.x;
    if (i >= n8) return;
    const float4* p = (const float4*)in;
    float4 a = p[2 * i], b = p[2 * i + 1];
    int4 w;
    w.x = packbf(a.x, a.y); w.y = packbf(a.z, a.w);
    w.z = packbf(b.x, b.y); w.w = packbf(b.z, b.w);
    ((int4*)out)[i] = w;
}

// ---------------------------------------------------------------------------
// fp32 [R][C] -> bf16 [C][R] transpose-convert. 64x64 tiles, padded LDS.
// ---------------------------------------------------------------------------
__global__ __launch_bounds__(256)
void transpose_bf16_k(const float* __restrict__ in, unsigned short* __restrict__ out,
                      int R, int C)
{
    __shared__ float tile[64][65];
    const int r0 = blockIdx.y * 64, c0 = blockIdx.x * 64;
    const int tr = threadIdx.x >> 4;
    const int tc = (threadIdx.x & 15) * 4;
#pragma unroll
    for (int rr = 0; rr < 64; rr += 16) {
        float4 v = *(const float4*)(in + (size_t)(r0 + tr + rr) * C + c0 + tc);
        tile[tr + rr][tc + 0] = v.x; tile[tr + rr][tc + 1] = v.y;
        tile[tr + rr][tc + 2] = v.z; tile[tr + rr][tc + 3] = v.w;
    }
    __syncthreads();
    const int ow = threadIdx.x >> 2;
    const int os = (threadIdx.x & 3) * 16;
    int4 w0, w1;
    float s[16];
#pragma unroll
    for (int e = 0; e < 16; ++e) s[e] = tile[os + e][ow];
    w0.x = packbf(s[0], s[1]);   w0.y = packbf(s[2], s[3]);
    w0.z = packbf(s[4], s[5]);   w0.w = packbf(s[6], s[7]);
    w1.x = packbf(s[8], s[9]);   w1.y = packbf(s[10], s[11]);
    w1.z = packbf(s[12], s[13]); w1.w = packbf(s[14], s[15]);
    unsigned short* orow = out + (size_t)(c0 + ow) * R + r0 + os;
    *(int4*)(orow) = w0;
    *(int4*)(orow + 8) = w1;
}

// ---------------------------------------------------------------------------
// QKV GEMM (round-7..9, measured-correct): epilogue routes bf16 into
// Qb (prescaled 0.125, [b,h,t,dh]), Kb ([b,h,t,dh]), Vtb ([b,h,dh,t]).
// ---------------------------------------------------------------------------
__global__ __launch_bounds__(256)
void gemm_qkv(const unsigned short* __restrict__ A,
              const unsigned short* __restrict__ Bt,
              unsigned short* __restrict__ Qb,
              unsigned short* __restrict__ Kb,
              unsigned short* __restrict__ Vtb,
              int M, int N, int K)
{
    __shared__ __align__(16) unsigned short As[2][128 * 32];
    __shared__ __align__(16) unsigned short Bs[2][128 * 32];

    const int tid = threadIdx.x;
    const int w = tid >> 6, l = tid & 63;
    const int lhi = l >> 4, llo = l & 15;
    const int wr = w >> 1, wc = w & 1;
    const int bm = blockIdx.y * 128, bn = blockIdx.x * 128;

    const int srow = w * 32 + (l >> 2);
    const int sg   = l & 3;

    const unsigned short* Ab = A + (size_t)bm * K;
    const unsigned short* Bb = Bt + (size_t)bn * K;

    f32x4 acc[4][4];
#pragma unroll
    for (int mi = 0; mi < 4; ++mi)
#pragma unroll
        for (int ni = 0; ni < 4; ++ni) acc[mi][ni] = (f32x4){0.f, 0.f, 0.f, 0.f};

    short8v a0r, a1r, b0r, b1r;
    const int nt = K >> 5;

#define LOADT(t) do {                                                        \
        const size_t ko = (size_t)(t) * 32 + sg * 8;                         \
        a0r = *(const short8v*)(Ab + (size_t)srow * K + ko);                 \
        a1r = *(const short8v*)(Ab + (size_t)(srow + 16) * K + ko);         \
        b0r = *(const short8v*)(Bb + (size_t)srow * K + ko);                 \
        b1r = *(const short8v*)(Bb + (size_t)(srow + 16) * K + ko);         \
    } while (0)
#define WRITET(buf) do {                                                     \
        *(short8v*)&As[buf][srow * 32 + (sg ^ GSWZ(srow)) * 8] = a0r;        \
        *(short8v*)&As[buf][(srow + 16) * 32 + (sg ^ GSWZ(srow + 16)) * 8] = a1r; \
        *(short8v*)&Bs[buf][srow * 32 + (sg ^ GSWZ(srow)) * 8] = b0r;        \
        *(short8v*)&Bs[buf][(srow + 16) * 32 + (sg ^ GSWZ(srow + 16)) * 8] = b1r; \
    } while (0)

    LOADT(0);
    WRITET(0);
    __syncthreads();

    int cur = 0;
    for (int t = 0; t < nt; ++t) {
        if (t + 1 < nt) LOADT(t + 1);
        short8v af[4], bfr[4];
#pragma unroll
        for (int mi = 0; mi < 4; ++mi) {
            const int m = wr * 64 + mi * 16 + llo;
            af[mi] = *(const short8v*)&As[cur][m * 32 + (lhi ^ GSWZ(m)) * 8];
        }
#pragma unroll
        for (int ni = 0; ni < 4; ++ni) {
            const int n = wc * 64 + ni * 16 + llo;
            bfr[ni] = *(const short8v*)&Bs[cur][n * 32 + (lhi ^ GSWZ(n)) * 8];
        }
#pragma unroll
        for (int mi = 0; mi < 4; ++mi)
#pragma unroll
            for (int ni = 0; ni < 4; ++ni)
                acc[mi][ni] = __builtin_amdgcn_mfma_f32_16x16x32_bf16(
                    af[mi], bfr[ni], acc[mi][ni], 0, 0, 0);
        if (t + 1 < nt) WRITET(cur ^ 1);
        __syncthreads();
        cur ^= 1;
    }
#undef LOADT
#undef WRITET

#pragma unroll
    for (int mi = 0; mi < 4; ++mi)
#pragma unroll
        for (int ni = 0; ni < 4; ++ni) {
            const int col = bn + wc * 64 + ni * 16 + llo;
            const int rb  = bm + wr * 64 + mi * 16 + lhi * 4;
            const int hh = (col >> 6) & 15;
            const int dh = col & 63;
            const int bb = rb >> 11;
            const int tt = rb & 2047;
            const int which = col >> 10;
            if (which == 2) {
                int2 pk;
                pk.x = packbf(acc[mi][ni][0], acc[mi][ni][1]);
                pk.y = packbf(acc[mi][ni][2], acc[mi][ni][3]);
                *(int2*)&Vtb[((size_t)(bb * H_ + hh) * DH_ + dh) * T_ + tt] = pk;
            } else {
                unsigned short* dst = (which == 0 ? Qb : Kb)
                    + ((size_t)(bb * H_ + hh) * T_ + tt) * DH_ + dh;
                const float sc = (which == 0) ? 0.125f : 1.f;
#pragma unroll
                for (int i = 0; i < 4; ++i)
                    dst[(size_t)i * DH_] = f2bf(acc[mi][ni][i] * sc);
            }
        }
}

// ---------------------------------------------------------------------------
// bf16 MFMA GEMM (round-6..9, measured-correct): C_f32 = A_bf16 @ Bt_bf16^T.
// ---------------------------------------------------------------------------
__global__ __launch_bounds__(256)
void gemm_bt_bf16(const unsigned short* __restrict__ A,
                  const unsigned short* __restrict__ Bt,
                  float* __restrict__ C, int M, int N, int K)
{
    __shared__ __align__(16) unsigned short As[2][128 * 32];
    __shared__ __align__(16) unsigned short Bs[2][128 * 32];

    const int tid = threadIdx.x;
    const int w = tid >> 6, l = tid & 63;
    const int lhi = l >> 4, llo = l & 15;
    const int wr = w >> 1, wc = w & 1;
    const int bm = blockIdx.y * 128, bn = blockIdx.x * 128;

    const int srow = w * 32 + (l >> 2);
    const int sg   = l & 3;

    const unsigned short* Ab = A + (size_t)bm * K;
    const unsigned short* Bb = Bt + (size_t)bn * K;

    f32x4 acc[4][4];
#pragma unroll
    for (int mi = 0; mi < 4; ++mi)
#pragma unroll
        for (int ni = 0; ni < 4; ++ni) acc[mi][ni] = (f32x4){0.f, 0.f, 0.f, 0.f};

    short8v a0r, a1r, b0r, b1r;
    const int nt = K >> 5;

#define LOADT(t) do {                                                        \
        const size_t ko = (size_t)(t) * 32 + sg * 8;                         \
        a0r = *(const short8v*)(Ab + (size_t)srow * K + ko);                 \
        a1r = *(const short8v*)(Ab + (size_t)(srow + 16) * K + ko);         \
        b0r = *(const short8v*)(Bb + (size_t)srow * K + ko);                 \
        b1r = *(const short8v*)(Bb + (size_t)(srow + 16) * K + ko);         \
    } while (0)
#define WRITET(buf) do {                                                     \
        *(short8v*)&As[buf][srow * 32 + (sg ^ GSWZ(srow)) * 8] = a0r;        \
        *(short8v*)&As[buf][(srow + 16) * 32 + (sg ^ GSWZ(srow + 16)) * 8] = a1r; \
        *(short8v*)&Bs[buf][srow * 32 + (sg ^ GSWZ(srow)) * 8] = b0r;        \
        *(short8v*)&Bs[buf][(srow + 16) * 32 + (sg ^ GSWZ(srow + 16)) * 8] = b1r; \
    } while (0)

    LOADT(0);
    WRITET(0);
    __syncthreads();

    int cur = 0;
    for (int t = 0; t < nt; ++t) {
        if (t + 1 < nt) LOADT(t + 1);
        short8v af[4], bfr[4];
#pragma unroll
        for (int mi = 0; mi < 4; ++mi) {
            const int m = wr * 64 + mi * 16 + llo;
            af[mi] = *(const short8v*)&As[cur][m * 32 + (lhi ^ GSWZ(m)) * 8];
        }
#pragma unroll
        for (int ni = 0; ni < 4; ++ni) {
            const int n = wc * 64 + ni * 16 + llo;
            bfr[ni] = *(const short8v*)&Bs[cur][n * 32 + (lhi ^ GSWZ(n)) * 8];
        }
#pragma unroll
        for (int mi = 0; mi < 4; ++mi)
#pragma unroll
            for (int ni = 0; ni < 4; ++ni)
                acc[mi][ni] = __builtin_amdgcn_mfma_f32_16x16x32_bf16(
                    af[mi], bfr[ni], acc[mi][ni], 0, 0, 0);
        if (t + 1 < nt) WRITET(cur ^ 1);
        __syncthreads();
        cur ^= 1;
    }
#undef LOADT
#undef WRITET

#pragma unroll
    for (int mi = 0; mi < 4; ++mi)
#pragma unroll
        for (int ni = 0; ni < 4; ++ni) {
            const int col = bn + wc * 64 + ni * 16 + llo;
            const int rb = bm + wr * 64 + mi * 16 + lhi * 4;
#pragma unroll
            for (int i = 0; i < 4; ++i)
                C[(size_t)(rb + i) * N + col] = acc[mi][ni][i];
        }
}

// ---------------------------------------------------------------------------
// bf16-MFMA flash attention, swapped operands (round-9, measured-correct),
// PLUS: (a) round-5's paired q-tiles (block bx does qt=bx and qt=31-bx ->
// every block exactly 33 tile-iters, every CU identical work regardless of
// dispatch mapping); (b) mask==1.0 fast path (block-uniform flag via
// __syncthreads_and) skipping 16 ms[] LDS reads + multiplies per wave-iter.
// Grid: (16, H, B) = 512 blocks.
// ---------------------------------------------------------------------------
__global__ __launch_bounds__(256, 4)
void attn_mfma(const unsigned short* __restrict__ Qb,
               const unsigned short* __restrict__ Kb,
               const unsigned short* __restrict__ Vtb,
               const float* __restrict__ mask,
               unsigned short* __restrict__ out)
{
    __shared__ __align__(16) unsigned short Ks[64 * 64];   // [key][dh] swz
    __shared__ __align__(16) unsigned short Vs[64 * 64];   // [dh][key] swz
    __shared__ __align__(16) unsigned short Pl[4][16 * 64];
    __shared__ float ms[64];

    const int tid = threadIdx.x;
    const int w = tid >> 6, l = tid & 63;
    const int lhi = l >> 4, llo = l & 15;
    const int b = blockIdx.z, h = blockIdx.y;

    const size_t bh = (size_t)(b * H_ + h);
    const unsigned short* Kbase = Kb + bh * T_ * DH_;
    const unsigned short* Vbase = Vtb + bh * DH_ * T_;

    const int sr  = tid >> 2;
    const int sg0 = (tid & 3) * 2;

    int4 kr0, kr1, vr0, vr1;
    float mval;
#define LOADKV(t) do {                                                       \
        const int kk = (t) * 64;                                             \
        const unsigned short* kp = Kbase + (size_t)(kk + sr) * DH_ + sg0 * 8;\
        kr0 = *(const int4*)(kp);                                            \
        kr1 = *(const int4*)(kp + 8);                                        \
        const unsigned short* vp = Vbase + (size_t)sr * T_ + kk + sg0 * 8;   \
        vr0 = *(const int4*)(vp);                                            \
        vr1 = *(const int4*)(vp + 8);                                        \
        mval = (tid < 64) ? mask[b * T_ + kk + tid] : 0.f;                   \
    } while (0)

    for (int qsel = 0; qsel < 2; ++qsel) {
        const int qt = qsel ? (31 - (int)blockIdx.x) : (int)blockIdx.x;
        const int qb = qt * 64;
        const int qg = qb + w * 16 + llo;     // this lane's query

        // Q B-frags (col=llo=q, k=lhi*8+e); prescale already applied
        short8v qf[2];
        {
            const unsigned short* qrow = Qb + (bh * T_ + qg) * DH_;
            qf[0] = *(const short8v*)(qrow + lhi * 8);
            qf[1] = *(const short8v*)(qrow + 32 + lhi * 8);
        }

        // acc = O^T: acc[ct2][i] = O[dh=16ct2+4lhi+i][q=llo]
        f32x4 acc[4];
#pragma unroll
        for (int ct = 0; ct < 4; ++ct) acc[ct] = (f32x4){0.f, 0.f, 0.f, 0.f};
        float mrun = -INFINITY, lrun = 0.f;

        LOADKV(0);

        for (int t0 = 0; t0 <= qt; ++t0) {
            const int k0 = t0 * 64;
            *(int4*)&Ks[(sr * 8 + (sg0 ^ SWZ(sr))) * 8] = kr0;
            *(int4*)&Ks[(sr * 8 + ((sg0 + 1) ^ SWZ(sr))) * 8] = kr1;
            *(int4*)&Vs[(sr * 8 + (sg0 ^ SWZ(sr))) * 8] = vr0;
            *(int4*)&Vs[(sr * 8 + ((sg0 + 1) ^ SWZ(sr))) * 8] = vr1;
            if (tid < 64) ms[tid] = mval;
            // barrier + block-uniform "mask all ones" flag
            const int allone =
                __syncthreads_and((tid >= 64) ? 1 : (mval == 1.0f));

            {
                const int tn = (t0 < qt) ? t0 + 1 : 0;
                LOADKV(tn);
            }

            // ---- S = K @ Q^T -> S[key][q]; lane: q=llo, keys 16ct+4lhi+i
            float p[4][4];
#pragma unroll
            for (int ct = 0; ct < 4; ++ct) {
                f32x4 a = (f32x4){0.f, 0.f, 0.f, 0.f};
#pragma unroll
                for (int kc = 0; kc < 2; ++kc) {
                    const int row = ct * 16 + llo;      // key row in Ks
                    const int G = kc * 4 + lhi;
                    short8v kf = *(const short8v*)&Ks[(row * 8 + (G ^ SWZ(row))) * 8];
                    a = __builtin_amdgcn_mfma_f32_16x16x32_bf16(kf, qf[kc], a, 0, 0, 0);
                }
                if (allone) {
#pragma unroll
                    for (int i = 0; i < 4; ++i) {
                        const int kg = k0 + ct * 16 + 4 * lhi + i;
                        p[ct][i] = (kg <= qg) ? a[i] : -INFINITY;
                    }
                } else {
#pragma unroll
                    for (int i = 0; i < 4; ++i) {
                        const int kg = k0 + ct * 16 + 4 * lhi + i;
                        const float amv = ms[ct * 16 + 4 * lhi + i];
                        const float s = a[i] * amv;
                        p[ct][i] = (kg <= qg && amv != 0.f) ? s : -INFINITY;
                    }
                }
            }

            // ---- online softmax: in-lane 16-reduce + 2-deep shfl ----
            float mx;
            {
                float m0 = fmaxf(fmaxf(p[0][0], p[0][1]), fmaxf(p[0][2], p[0][3]));
                float m1 = fmaxf(fmaxf(p[1][0], p[1][1]), fmaxf(p[1][2], p[1][3]));
                float m2 = fmaxf(fmaxf(p[2][0], p[2][1]), fmaxf(p[2][2], p[2][3]));
                float m3 = fmaxf(fmaxf(p[3][0], p[3][1]), fmaxf(p[3][2], p[3][3]));
                mx = fmaxf(fmaxf(m0, m1), fmaxf(m2, m3));
            }
            mx = fmaxf(mx, __shfl_xor(mx, 16));
            mx = fmaxf(mx, __shfl_xor(mx, 32));
            const float mn = fmaxf(mrun, mx);
            const float me = (mn > -INFINITY) ? mn : 0.f;
            const float corr = __expf(mrun - me);
            mrun = mn;

#pragma unroll
            for (int ct = 0; ct < 4; ++ct)
#pragma unroll
                for (int i = 0; i < 4; ++i)
                    p[ct][i] = __expf(p[ct][i] - me);   // exp(-inf)=0

            float sm;
            {
                float s0 = (p[0][0] + p[0][1]) + (p[0][2] + p[0][3]);
                float s1 = (p[1][0] + p[1][1]) + (p[1][2] + p[1][3]);
                float s2 = (p[2][0] + p[2][1]) + (p[2][2] + p[2][3]);
                float s3 = (p[3][0] + p[3][1]) + (p[3][2] + p[3][3]);
                sm = (s0 + s1) + (s2 + s3);
            }
            sm += __shfl_xor(sm, 16);
            sm += __shfl_xor(sm, 32);
            lrun = corr * lrun + sm;
#pragma unroll
            for (int ct2 = 0; ct2 < 4; ++ct2)
#pragma unroll
                for (int i = 0; i < 4; ++i)
                    acc[ct2][i] *= corr;

            // ---- P -> Pl[q=llo][key], packed int2 writes ----
            unsigned short* pw = Pl[w];
#pragma unroll
            for (int ct = 0; ct < 4; ++ct) {
                int2 pk;
                pk.x = packbf(p[ct][0], p[ct][1]);
                pk.y = packbf(p[ct][2], p[ct][3]);
                const int k3 = 2 * ct + (lhi >> 1);   // key>>3
                *(int2*)&pw[(llo * 8 + (k3 ^ SWZ(llo))) * 8 + 4 * (lhi & 1)] = pk;
            }
            asm volatile("s_waitcnt lgkmcnt(0)" ::: "memory");
            __builtin_amdgcn_sched_barrier(0);   // rule #18
            short8v pf[2];
#pragma unroll
            for (int kc = 0; kc < 2; ++kc) {
                const int G = kc * 4 + lhi;
                pf[kc] = *(const short8v*)&pw[(llo * 8 + (G ^ SWZ(llo))) * 8];
            }

            // ---- O^T += V^T @ P ----
#pragma unroll
            for (int ct2 = 0; ct2 < 4; ++ct2) {
#pragma unroll
                for (int kc = 0; kc < 2; ++kc) {
                    const int row = ct2 * 16 + llo;     // Vs row = dh
                    const int G = kc * 4 + lhi;
                    short8v vf = *(const short8v*)&Vs[(row * 8 + (G ^ SWZ(row))) * 8];
                    acc[ct2] = __builtin_amdgcn_mfma_f32_16x16x32_bf16(
                        vf, pf[kc], acc[ct2], 0, 0, 0);
                }
            }
            __syncthreads();
        }

        // ---- epilogue: normalize, transpose O^T via wave-private Pl ----
        {
            const float invl = (lrun > 0.f) ? 1.f / lrun : 0.f;
            unsigned short* pw = Pl[w];
#pragma unroll
            for (int ct2 = 0; ct2 < 4; ++ct2) {
                int2 ok;
                ok.x = packbf(acc[ct2][0] * invl, acc[ct2][1] * invl);
                ok.y = packbf(acc[ct2][2] * invl, acc[ct2][3] * invl);
                const int d3 = 2 * ct2 + (lhi >> 1);   // dh>>3
                *(int2*)&pw[(llo * 8 + (d3 ^ SWZ(llo))) * 8 + 4 * (lhi & 1)] = ok;
            }
            asm volatile("s_waitcnt lgkmcnt(0)" ::: "memory");
            __builtin_amdgcn_sched_barrier(0);
            const int r  = l >> 2;           // q row within wave
            const int g2 = (l & 3) * 2;      // dh granule pair
            short8v o0 = *(const short8v*)&pw[(r * 8 + (g2 ^ SWZ(r))) * 8];
            short8v o1 = *(const short8v*)&pw[(r * 8 + ((g2 + 1) ^ SWZ(r))) * 8];
            unsigned short* orow = out
                + (size_t)(b * T_ + qb + w * 16 + r) * (H_ * DH_)
                + h * DH_ + (l & 3) * 16;
            *(short8v*)(orow) = o0;
            *(short8v*)(orow + 8) = o1;
        }
    }
#undef LOADKV
}

// ---------------------------------------------------------------------------
extern "C" void kernel_launch(void* const* d_in, const int* in_sizes, int n_in,
                              void* d_out, int out_size, void* d_ws, size_t ws_size,
                              hipStream_t stream)
{
    const float* x    = (const float*)d_in[0];
    const float* Wqkv = (const float*)d_in[1];
    const float* Wo   = (const float*)d_in[2];
    const float* mask = (const float*)d_in[3];
    float* out = (float*)d_out;

    // workspace layout (~48 MB)
    char* p = (char*)d_ws;
    unsigned short* xb     = (unsigned short*)p; p += (size_t)NROWS * D_ * 2;
    unsigned short* wqkv_t = (unsigned short*)p; p += (size_t)QKV_N * D_ * 2;
    unsigned short* wo_t   = (unsigned short*)p; p += (size_t)D_ * D_ * 2;
    unsigned short* Qb     = (unsigned short*)p; p += (size_t)NROWS * D_ * 2;
    unsigned short* Kb     = (unsigned short*)p; p += (size_t)NROWS * D_ * 2;
    unsigned short* Vtb    = (unsigned short*)p; p += (size_t)NROWS * D_ * 2;
    unsigned short* attnb  = (unsigned short*)p;

    f32_to_bf16_k<<<(NROWS * D_ / 8 + 255) / 256, 256, 0, stream>>>(
        x, xb, NROWS * D_ / 8);
    transpose_bf16_k<<<dim3(QKV_N / 64, D_ / 64), 256, 0, stream>>>(
        Wqkv, wqkv_t, D_, QKV_N);
    transpose_bf16_k<<<dim3(D_ / 64, D_ / 64), 256, 0, stream>>>(
        Wo, wo_t, D_, D_);

    gemm_qkv<<<dim3(QKV_N / 128, NROWS / 128), 256, 0, stream>>>(
        xb, wqkv_t, Qb, Kb, Vtb, NROWS, QKV_N, D_);

    attn_mfma<<<dim3(16, H_, B_), 256, 0, stream>>>(Qb, Kb, Vtb, mask, attnb);

    gemm_bt_bf16<<<dim3(D_ / 128, NROWS / 128), 256, 0, stream>>>(
        attnb, wo_t, out, NROWS, D_, H_ * DH_);
}